// Round 12
// baseline (17.970 us; speedup 1.0000x reference)
//
#include <hip/hip_runtime.h>
#include <math.h>

#define N_ 2
#define C_ 32
#define X_ 48
#define Y_ 48
#define Z_ 24
#define M_ (X_*Y_*Z_)   // 55296

#define TX_ 2
#define TY_ 4
#define TZ_ 12
#define HX_ (TX_+2)          // 4
#define HY_ (TY_+2)          // 6
#define HZ_ (TZ_+2)          // 14
#define HVOX_ (HX_*HY_*HZ_)  // 336 halo voxels
#define TVOX_ (TX_*TY_*TZ_)  // 96 output voxels
#define THREADS_ 192         // 2 threads per output voxel (channel halves)
#define NXT_ (X_/TX_)        // 24
#define NYT_ (Y_/TY_)        // 12
#define NZT_ (Z_/TZ_)        // 2
#define NWG_ (NXT_*NYT_*NZT_*N_)  // 1152, divisible by 8 -> chunk 144

typedef _Float16 h2 __attribute__((ext_vector_type(2)));

#if __has_builtin(__builtin_amdgcn_fdot2)
__device__ __forceinline__ float dot2(h2 a, h2 b, float c) {
    return __builtin_amdgcn_fdot2(a, b, c, false);
}
#else
__device__ __forceinline__ float dot2(h2 a, h2 b, float c) {
    return fmaf((float)a[1], (float)b[1], fmaf((float)a[0], (float)b[0], c));
}
#endif

// exp in log2 domain: fold log2(e) into the logit scale, use raw v_exp_f32.
// invalid offsets keep logit 0 -> exp2(0) = 1, matching exp(0) = 1.
#if __has_builtin(__builtin_amdgcn_exp2f)
#define EXPFN_(x) __builtin_amdgcn_exp2f(x)
#define LOGSCALE_ 1.44269504f
#else
#define EXPFN_(x) __expf(x)
#define LOGSCALE_ 1.0f
#endif

// R10/R11 structure, tile z-halved to 2x4x12 (halo redundancy 4.0x -> 3.5x,
// staged voxels/block 384 -> 336, LDS 24.6 -> 21.5 KB => 7 blocks/CU).
// R7 tried this shape but bundled two poisons (launch_bounds(192,6) VGPR cap,
// per-quad staging); both removed here -- per-voxel coalesced staging,
// (192,4) bounds. XCD swizzle kept (1152 = 8*144, bijective).
__global__ __launch_bounds__(THREADS_, 4) void fused_kernel(
    const float* __restrict__ f0, const float* __restrict__ f1,
    const float* __restrict__ logit_scale, float* __restrict__ out)
{
    __shared__ int4 lds[HVOX_ * 4];   // 21,504 B

    const int tid = threadIdx.x;
    const int wgid = (blockIdx.x & 7) * (NWG_ / 8) + (blockIdx.x >> 3);
    const int n   = wgid / (NXT_ * NYT_ * NZT_);
    int rem = wgid - n * (NXT_ * NYT_ * NZT_);
    const int zt = rem % NZT_;  rem /= NZT_;
    const int xt = rem % NXT_;
    const int yt = rem / NXT_;
    const int x0 = xt * TX_;
    const int y0 = yt * TY_;
    const int z0 = zt * TZ_;

    // ---------------- Phase 1: f1 halo -> normalized fp16 in LDS ----------
    const float* f1b = f1 + (size_t)n * C_ * M_;
#pragma unroll
    for (int it = 0; it < 2; ++it) {
        int h = it * THREADS_ + tid;
        if (h < HVOX_) {
            int hx = h / (HY_ * HZ_);
            int rh = h - hx * (HY_ * HZ_);
            int hy = rh / HZ_;
            int hz = rh - hy * HZ_;
            int ggx = min(max(x0 - 1 + hx, 0), X_ - 1);
            int ggy = min(max(y0 - 1 + hy, 0), Y_ - 1);
            int ggz = min(max(z0 - 1 + hz, 0), Z_ - 1);
            int gm = (ggx * Y_ + ggy) * Z_ + ggz;

            float b[C_];
            float s = 0.f;
#pragma unroll
            for (int c = 0; c < C_; ++c) {
                b[c] = f1b[(size_t)c * M_ + gm];
                s = fmaf(b[c], b[c], s);
            }
            float rs = 1.0f / (sqrtf(s) + 1e-7f);
#pragma unroll
            for (int q = 0; q < 4; ++q) {        // quad q holds channels 8q..8q+7
                union { int4 qq; h2 hh[4]; } u;
#pragma unroll
                for (int e = 0; e < 4; ++e) {
                    h2 v2;
                    v2[0] = (_Float16)(b[8 * q + 2 * e]     * rs);
                    v2[1] = (_Float16)(b[8 * q + 2 * e + 1] * rs);
                    u.hh[e] = v2;
                }
                lds[h * 4 + (q ^ ((h >> 1) & 3))] = u.qq;   // bank swizzle
            }
        }
    }
    __syncthreads();

    // ---------------- Phase 2: per-voxel dots + softmax --------------------
    const int lane = tid & 63;
    const int w    = tid >> 6;
    const int hi   = lane >> 5;          // channel half
    const int slot = lane & 31;
    const int ov   = w * 32 + slot;      // 0..95, tz-consecutive
    const int tz   = ov % TZ_;
    const int txy  = ov / TZ_;
    const int ty   = txy % TY_;
    const int tx   = txy / TY_;
    const int gx = x0 + tx, gy = y0 + ty, gz = z0 + tz;
    const int gm = (gx * Y_ + gy) * Z_ + gz;

    // own 16 raw f0 channels; cross-half norm reduce
    const float* p0 = f0 + (size_t)n * C_ * M_ + (size_t)hi * 16 * M_ + gm;
    float a[16];
    float s0 = 0.f;
#pragma unroll
    for (int i = 0; i < 16; ++i) {
        a[i] = p0[(size_t)i * M_];
        s0 = fmaf(a[i], a[i], s0);
    }
    s0 += __shfl_xor(s0, 32, 64);
    float rs0 = __expf(logit_scale[0]) * LOGSCALE_ / (sqrtf(s0) + 1e-7f);
    h2 A[8];
#pragma unroll
    for (int i = 0; i < 8; ++i) {
        h2 v;
        v[0] = (_Float16)(a[2 * i]     * rs0);
        v[1] = (_Float16)(a[2 * i + 1] * rs0);
        A[i] = v;
    }

    float S = 0.f, FX = 0.f, FY = 0.f, FZ = 0.f;
#pragma unroll
    for (int i = 0; i < 3; ++i)
#pragma unroll
    for (int j = 0; j < 3; ++j)
#pragma unroll
    for (int k = 0; k < 3; ++k) {
        bool val = (gx + i - 1 >= 0) & (gx + i - 1 < X_) &
                   (gy + j - 1 >= 0) & (gy + j - 1 < Y_) &
                   (gz + k - 1 >= 0) & (gz + k - 1 < Z_);
        int v  = ((tx + i) * HY_ + (ty + j)) * HZ_ + (tz + k);
        union { int4 qq; h2 hh[4]; } B0, B1;
        int vx = (v >> 1) & 3;
        B0.qq = lds[v * 4 + ((2 * hi)     ^ vx)];
        B1.qq = lds[v * 4 + ((2 * hi + 1) ^ vx)];
        float d = 0.f;
#pragma unroll
        for (int e = 0; e < 4; ++e) d = dot2(A[e],     B0.hh[e], d);
#pragma unroll
        for (int e = 0; e < 4; ++e) d = dot2(A[4 + e], B1.hh[e], d);
        d += __shfl_xor(d, 32, 64);          // full 32-channel dot
        d = val ? d : 0.0f;                  // invalid -> logit exactly 0
        float e_ = EXPFN_(d);                // |log2-logit| <= 20.6, exp2 safe
        S += e_;
        if (i == 0) FX -= e_; else if (i == 2) FX += e_;
        if (j == 0) FY -= e_; else if (j == 2) FY += e_;
        if (k == 0) FZ -= e_; else if (k == 2) FZ += e_;
    }

    if (hi == 0) {
        float inv = 1.0f / S;
        size_t ob = ((size_t)n * M_ + gm) * 3;
        out[ob + 0] = FX * inv;
        out[ob + 1] = FY * inv;
        out[ob + 2] = FZ * inv;
    }
}

extern "C" void kernel_launch(void* const* d_in, const int* in_sizes, int n_in,
                              void* d_out, int out_size, void* d_ws, size_t ws_size,
                              hipStream_t stream) {
    const float* f0 = (const float*)d_in[0];
    const float* f1 = (const float*)d_in[1];
    const float* ls = (const float*)d_in[3];
    float* out = (float*)d_out;

    fused_kernel<<<NWG_, THREADS_, 0, stream>>>(f0, f1, ls, out);
}

// Round 13
// 15.907 us; speedup vs baseline: 1.1297x; 1.1297x over previous
//
#include <hip/hip_runtime.h>
#include <math.h>

#define N_ 2
#define C_ 32
#define X_ 48
#define Y_ 48
#define Z_ 24
#define M_ (X_*Y_*Z_)   // 55296

#define TX_ 2
#define TY_ 2
#define HX_ (TX_+2)          // 4
#define HY_ (TY_+2)          // 4
#define HVOX_ (HX_*HY_*Z_)   // 384 halo voxels
#define TVOX_ (TX_*TY_*Z_)   // 96 output voxels
#define THREADS_ 192         // 2 threads per output voxel (channel halves)
#define NXT_ (X_/TX_)        // 24
#define NYT_ (Y_/TY_)        // 24
#define NWG_ (NXT_*NYT_*N_)  // 1152, divisible by 8 XCDs -> chunk = 144

typedef _Float16 h2 __attribute__((ext_vector_type(2)));

#if __has_builtin(__builtin_amdgcn_fdot2)
__device__ __forceinline__ float dot2(h2 a, h2 b, float c) {
    return __builtin_amdgcn_fdot2(a, b, c, false);
}
#else
__device__ __forceinline__ float dot2(h2 a, h2 b, float c) {
    return fmaf((float)a[1], (float)b[1], fmaf((float)a[0], (float)b[0], c));
}
#endif

// exp in log2 domain: fold log2(e) into rs0, use raw v_exp_f32 (saves the
// per-call range-scaling mul __expf inserts). Invalid offsets keep logit 0:
// exp2(0) = 1 == exp(0), so softmax semantics are unchanged.
#if __has_builtin(__builtin_amdgcn_exp2f)
#define EXPFN_(x) __builtin_amdgcn_exp2f(x)
#define LOG2E_ 1.44269504f
#else
#define EXPFN_(x) __expf(x)
#define LOG2E_ 1.0f
#endif

// R11 structure (best measured: 16.0 us), only change: log2-domain exp.
//  - tile 2x2x24 (full z: phase-1 lane-consecutive halo voxels = contiguous
//    96B z-columns; z-split tiles fragment coalescing -- R12 regression)
//  - 1152 blocks, XCD-chunked swizzle (bijective, 1152 = 8*144): x/y-neighbor
//    tiles share an XCD -> halo re-reads hit the 4MB private L2
//  - phase 1: per-voxel staging (1 thread x 32ch), coalesced; fp16 voxel-major
//    in LDS, XOR-swizzled 16B quads (conflict-free, SQ_LDS_BANK_CONFLICT=0)
//  - phase 2: 2 threads/voxel (channel halves), 27 neighbor dots, online
//    no-max softmax (|logit| <= 14.29 -> exp safe without max subtraction)
__global__ __launch_bounds__(THREADS_, 4) void fused_kernel(
    const float* __restrict__ f0, const float* __restrict__ f1,
    const float* __restrict__ logit_scale, float* __restrict__ out)
{
    __shared__ int4 lds[HVOX_ * 4];   // 24,576 B

    const int tid = threadIdx.x;
    const int wgid = (blockIdx.x & 7) * (NWG_ / 8) + (blockIdx.x >> 3);
    const int n   = wgid / (NXT_ * NYT_);
    const int rem = wgid - n * (NXT_ * NYT_);
    const int xt  = rem % NXT_;
    const int yt  = rem / NXT_;
    const int x0  = xt * TX_;
    const int y0  = yt * TY_;

    // ---------------- Phase 1: f1 halo -> normalized fp16 in LDS ----------
    const float* f1b = f1 + (size_t)n * C_ * M_;
#pragma unroll
    for (int it = 0; it < 2; ++it) {
        int h = it * THREADS_ + tid;          // HVOX_ = 2*THREADS_, exact
        int hx = h / (HY_ * Z_);
        int rh = h - hx * (HY_ * Z_);
        int hy = rh / Z_;
        int hz = rh - hy * Z_;
        int gx = min(max(x0 - 1 + hx, 0), X_ - 1);
        int gy = min(max(y0 - 1 + hy, 0), Y_ - 1);
        int gm = (gx * Y_ + gy) * Z_ + hz;

        float b[C_];
        float s = 0.f;
#pragma unroll
        for (int c = 0; c < C_; ++c) {
            b[c] = f1b[(size_t)c * M_ + gm];
            s = fmaf(b[c], b[c], s);
        }
        float rs = 1.0f / (sqrtf(s) + 1e-7f);
#pragma unroll
        for (int q = 0; q < 4; ++q) {            // quad q holds channels 8q..8q+7
            union { int4 qq; h2 hh[4]; } u;
#pragma unroll
            for (int e = 0; e < 4; ++e) {
                h2 v2;
                v2[0] = (_Float16)(b[8 * q + 2 * e]     * rs);
                v2[1] = (_Float16)(b[8 * q + 2 * e + 1] * rs);
                u.hh[e] = v2;
            }
            lds[h * 4 + (q ^ ((h >> 1) & 3))] = u.qq;   // bank swizzle
        }
    }
    __syncthreads();

    // ---------------- Phase 2: per-voxel dots + softmax --------------------
    const int lane = tid & 63;
    const int w    = tid >> 6;
    const int hi   = lane >> 5;          // channel half
    const int slot = lane & 31;
    const int ov   = w * 32 + slot;      // 0..95, tz-consecutive
    const int tz   = ov % Z_;
    const int txy  = ov / Z_;
    const int ty   = txy % TY_;
    const int tx   = txy / TY_;
    const int gx = x0 + tx, gy = y0 + ty, gz = tz;
    const int gm = (gx * Y_ + gy) * Z_ + gz;

    // own 16 raw f0 channels; cross-half norm reduce
    const float* p0 = f0 + (size_t)n * C_ * M_ + (size_t)hi * 16 * M_ + gm;
    float a[16];
    float s0 = 0.f;
#pragma unroll
    for (int i = 0; i < 16; ++i) {
        a[i] = p0[(size_t)i * M_];
        s0 = fmaf(a[i], a[i], s0);
    }
    s0 += __shfl_xor(s0, 32, 64);
    float rs0 = __expf(logit_scale[0]) * LOG2E_ / (sqrtf(s0) + 1e-7f);
    h2 A[8];
#pragma unroll
    for (int i = 0; i < 8; ++i) {
        h2 v;
        v[0] = (_Float16)(a[2 * i]     * rs0);
        v[1] = (_Float16)(a[2 * i + 1] * rs0);
        A[i] = v;
    }

    float S = 0.f, FX = 0.f, FY = 0.f, FZ = 0.f;
#pragma unroll
    for (int i = 0; i < 3; ++i)
#pragma unroll
    for (int j = 0; j < 3; ++j)
#pragma unroll
    for (int k = 0; k < 3; ++k) {
        bool val = (gx + i - 1 >= 0) & (gx + i - 1 < X_) &
                   (gy + j - 1 >= 0) & (gy + j - 1 < Y_) &
                   (gz + k - 1 >= 0) & (gz + k - 1 < Z_);
        int hz = min(max(tz + k - 1, 0), Z_ - 1);
        int v  = (tx + i) * (HY_ * Z_) + (ty + j) * Z_ + hz;
        union { int4 qq; h2 hh[4]; } B0, B1;
        int vx = (v >> 1) & 3;
        B0.qq = lds[v * 4 + ((2 * hi)     ^ vx)];
        B1.qq = lds[v * 4 + ((2 * hi + 1) ^ vx)];
        float d = 0.f;
#pragma unroll
        for (int e = 0; e < 4; ++e) d = dot2(A[e],     B0.hh[e], d);
#pragma unroll
        for (int e = 0; e < 4; ++e) d = dot2(A[4 + e], B1.hh[e], d);
        d += __shfl_xor(d, 32, 64);          // full 32-channel dot
        d = val ? d : 0.0f;                  // invalid -> logit exactly 0
        float e_ = EXPFN_(d);                // log2-domain; |arg| <= 20.6, safe
        S += e_;
        if (i == 0) FX -= e_; else if (i == 2) FX += e_;
        if (j == 0) FY -= e_; else if (j == 2) FY += e_;
        if (k == 0) FZ -= e_; else if (k == 2) FZ += e_;
    }

    if (hi == 0) {
        float inv = 1.0f / S;
        size_t ob = ((size_t)n * M_ + gm) * 3;
        out[ob + 0] = FX * inv;
        out[ob + 1] = FY * inv;
        out[ob + 2] = FZ * inv;
    }
}

extern "C" void kernel_launch(void* const* d_in, const int* in_sizes, int n_in,
                              void* d_out, int out_size, void* d_ws, size_t ws_size,
                              hipStream_t stream) {
    const float* f0 = (const float*)d_in[0];
    const float* f1 = (const float*)d_in[1];
    const float* ls = (const float*)d_in[3];
    float* out = (float*)d_out;

    fused_kernel<<<NWG_, THREADS_, 0, stream>>>(f0, f1, ls, out);
}